// Round 11
// baseline (244.614 us; speedup 1.0000x reference)
//
#include <hip/hip_runtime.h>
#include <hip/hip_bf16.h>
#include <hip/hip_fp16.h>
#include <stdint.h>

#define B_SIZE 8192
#define D_SIZE 2048
#define C_SIZE 128
#define N_INNER 255
#define N_LEAF 256
#define NBLK_PATH 512

typedef _Float16 half8 __attribute__((ext_vector_type(8)));
typedef __fp16 pk16x2 __attribute__((ext_vector_type(2)));   // return type of cvt_pkrtz
typedef float f32x4 __attribute__((ext_vector_type(4)));
typedef unsigned short u16;

// ---- fp32 -> (hi,lo) fp16 split, packed pairs ----
__device__ inline uint32_t pkh(float a, float b) {
    pk16x2 h = __builtin_amdgcn_cvt_pkrtz(a, b);
    return __builtin_bit_cast(uint32_t, h);
}
__device__ inline void split4(const float4 v, uint2& hi, uint2& lo) {
    pk16x2 a01 = __builtin_amdgcn_cvt_pkrtz(v.x, v.y);
    pk16x2 a23 = __builtin_amdgcn_cvt_pkrtz(v.z, v.w);
    float r0 = v.x - (float)a01[0];
    float r1 = v.y - (float)a01[1];
    float r2 = v.z - (float)a23[0];
    float r3 = v.w - (float)a23[1];
    hi = make_uint2(__builtin_bit_cast(uint32_t, a01), __builtin_bit_cast(uint32_t, a23));
    lo = make_uint2(pkh(r0, r1), pkh(r2, r3));
}

// ---------------- K-pre (merged): split W -> Wh/Wl  AND  softmax -> Q, logQt ----------------
// W-split reinstated (R4 form): the fused gemm_path kernel is thin-tiled, so B must come
// pre-split from L2 to keep per-kt VALU off the critical path.
__global__ __launch_bounds__(256) void prep_kernel(
    const float* __restrict__ Wsrc, u16* __restrict__ Wh, u16* __restrict__ Wl,
    const float* __restrict__ lp, float* __restrict__ Q, float* __restrict__ logQt)
{
    int bid = blockIdx.x;
    int t = threadIdx.x;
    if (bid < 256) {
        int row = bid;
        int k = t * 8;
        uint2 h0, l0, h1, l1;
        if (row < N_INNER) {
            float4 v0 = *(const float4*)(Wsrc + (size_t)row * D_SIZE + k);
            float4 v1 = *(const float4*)(Wsrc + (size_t)row * D_SIZE + k + 4);
            split4(v0, h0, l0); split4(v1, h1, l1);
        } else {
            h0 = l0 = h1 = l1 = make_uint2(0u, 0u);   // row 255: zeros -> z col 255 = 0 (never consumed)
        }
        *(uint2*)&Wh[(size_t)row * D_SIZE + k]     = h0;
        *(uint2*)&Wh[(size_t)row * D_SIZE + k + 4] = h1;
        *(uint2*)&Wl[(size_t)row * D_SIZE + k]     = l0;
        *(uint2*)&Wl[(size_t)row * D_SIZE + k + 4] = l1;
    } else {
        // softmax over leaf row (bid-256)
        int row = bid - 256;
        __shared__ float red[128];
        float v = 0.f;
        if (t < 128) { v = lp[row * C_SIZE + t]; red[t] = v; }
        __syncthreads();
        for (int s = 64; s > 0; s >>= 1) { if (t < s) red[t] = fmaxf(red[t], red[t + s]); __syncthreads(); }
        float mx = red[0]; __syncthreads();
        float e = 0.f;
        if (t < 128) { e = expf(v - mx); red[t] = e; }
        __syncthreads();
        for (int s = 64; s > 0; s >>= 1) { if (t < s) red[t] += red[t + s]; __syncthreads(); }
        float sum = red[0];
        if (t < 128) {
            Q[row * C_SIZE + t] = e / sum;
            logQt[(size_t)t * N_LEAF + row] = (v - mx) - logf(sum);   // [class][leaf]
        }
    }
}

// ---------------- K1 (FUSED): full-K GEMM + path epilogue — z round-trip ELIMINATED ----------------
// BM=16, full K=2048 per block (KSPLIT=1), grid 512 blocks = 2 blocks/CU (proven density).
// Per wave: acc[4] (16x64 of z), A via wave-private LDS + lgkm fence (R0 pattern), A+B
// one-deep reg prefetch (clamped at the tail so the loop body is branch-free).
// Epilogue: acc -> zbuf[16][256] in LDS, ONE barrier, then each wave runs the path body
// (sigmoid in-place + factored tree walks) on its 4 rows. Block<->row mapping identical to
// the old path_kernel -> partial records and reduce_kernel unchanged.
// NOTE: launch_bounds min-waves MUST stay 2 — (256,4) squeezes arch-VGPR to 64 and
// spills ~1.1 GB scratch (R5: 380 us). Do not raise it.
#define FBM 16
#define FBK 32
#define FKIT (D_SIZE / FBK)   // 64
#define LDKA 40               // padded A row stride in u16 (80 B -> 2-way bank alias = free)

__global__ __launch_bounds__(256, 2) void gemm_path(
    const float* __restrict__ x, const u16* __restrict__ Wh, const u16* __restrict__ Wl,
    const int* __restrict__ target, const float* __restrict__ bvec, const float* __restrict__ beta,
    const float* __restrict__ Q, const float* __restrict__ logQt,
    float* __restrict__ partial, float* __restrict__ out)
{
    __shared__ __align__(16) u16 sAh[4][FBM * LDKA];
    __shared__ __align__(16) u16 sAl[4][FBM * LDKA];
    __shared__ float zbuf[FBM][256];
    __shared__ float s_num[128], s_den[128], s_loss;

    const int t = threadIdx.x;
    const int lane = t & 63, w = t >> 6;
    const int lr = lane & 15, lq = lane >> 4;
    const int m0 = blockIdx.x * FBM;

    if (t < 128) s_num[t] = 0.f;
    else s_den[t - 128] = 0.f;
    if (t == 0) s_loss = 0.f;
    // visibility of the init is covered by the epilogue __syncthreads

    f32x4 acc[4];
    #pragma unroll
    for (int nt = 0; nt < 4; ++nt) acc[nt] = (f32x4){0.f, 0.f, 0.f, 0.f};

    // prologue: first A tile (16 rows x 32 k fp32, 2 float4/lane, 8 lanes/row coalesced)
    float4 av_c[2];
    #pragma unroll
    for (int i = 0; i < 2; ++i) {
        int idx = i * 64 + lane;
        int row = idx >> 3, ch = idx & 7;
        av_c[i] = *(const float4*)(x + (size_t)(m0 + row) * D_SIZE + ch * 4);
    }
    // prologue: kt=0 B fragments (pre-split, L2-resident)
    half8 bh[4], bl[4];
    #pragma unroll
    for (int nt = 0; nt < 4; ++nt) {
        int row = w * 64 + nt * 16 + lr;
        bh[nt] = *(const half8*)(Wh + (size_t)row * D_SIZE + lq * 8);
        bl[nt] = *(const half8*)(Wl + (size_t)row * D_SIZE + lq * 8);
    }

    #pragma unroll 4
    for (int kt = 0; kt < FKIT; ++kt) {
        const int kb = kt * FBK;
        const int kn = (kt + 1 < FKIT) ? kb + FBK : kb;   // clamped prefetch (tail re-read, discarded)
        // 1. issue next B loads
        half8 nbh[4], nbl[4];
        #pragma unroll
        for (int nt = 0; nt < 4; ++nt) {
            int row = w * 64 + nt * 16 + lr;
            nbh[nt] = *(const half8*)(Wh + (size_t)row * D_SIZE + kn + lq * 8);
            nbl[nt] = *(const half8*)(Wl + (size_t)row * D_SIZE + kn + lq * 8);
        }
        // 2. issue next A loads
        float4 av_n[2];
        #pragma unroll
        for (int i = 0; i < 2; ++i) {
            int idx = i * 64 + lane;
            int row = idx >> 3, ch = idx & 7;
            av_n[i] = *(const float4*)(x + (size_t)(m0 + row) * D_SIZE + kn + ch * 4);
        }
        // 3. split current A into this wave's private LDS region
        #pragma unroll
        for (int i = 0; i < 2; ++i) {
            int idx = i * 64 + lane;
            int row = idx >> 3, ch = idx & 7;
            uint2 hi, lo; split4(av_c[i], hi, lo);
            *(uint2*)&sAh[w][row * LDKA + ch * 4] = hi;
            *(uint2*)&sAl[w][row * LDKA + ch * 4] = lo;
        }
        asm volatile("s_waitcnt lgkmcnt(0)" ::: "memory");  // wave-sync LDS: writes visible to own wave
        // 4. A fragments (single 16-row tile: row = lr)
        half8 ah = *(const half8*)&sAh[w][lr * LDKA + lq * 8];
        half8 al = *(const half8*)&sAl[w][lr * LDKA + lq * 8];
        // 5. MFMA (hi*hi + hi*lo + lo*hi)
        #pragma unroll
        for (int nt = 0; nt < 4; ++nt) {
            acc[nt] = __builtin_amdgcn_mfma_f32_16x16x32_f16(ah, bh[nt], acc[nt], 0, 0, 0);
            acc[nt] = __builtin_amdgcn_mfma_f32_16x16x32_f16(ah, bl[nt], acc[nt], 0, 0, 0);
            acc[nt] = __builtin_amdgcn_mfma_f32_16x16x32_f16(al, bh[nt], acc[nt], 0, 0, 0);
        }
        // 6. rotate prefetched A and B into current
        #pragma unroll
        for (int i = 0; i < 2; ++i) av_c[i] = av_n[i];
        #pragma unroll
        for (int nt = 0; nt < 4; ++nt) { bh[nt] = nbh[nt]; bl[nt] = nbl[nt]; }
    }

    // ---- epilogue phase A: acc -> zbuf (waves write disjoint 64-col slices) ----
    #pragma unroll
    for (int nt = 0; nt < 4; ++nt) {
        int gn = w * 64 + nt * 16 + lr;
        #pragma unroll
        for (int r = 0; r < 4; ++r)
            zbuf[lq * 4 + r][gn] = acc[nt][r];
    }
    __syncthreads();

    // ---- epilogue phase B: path body; wave w owns local rows w*4..w*4+3 ----
    const int c0 = lane * 4;
    float bet[4], bia[4];
    #pragma unroll
    for (int j = 0; j < 4; ++j) {
        int c = c0 + j;
        bet[j] = (c < N_INNER) ? beta[c] : 0.f;
        bia[j] = (c < N_INNER) ? bvec[c] : 0.f;
    }
    int tg[4];
    #pragma unroll
    for (int i = 0; i < 4; ++i) tg[i] = target[m0 + w * 4 + i];

    // sigmoid in place (each lane owns cols c0..c0+3 of each of its wave's 4 rows)
    #pragma unroll
    for (int i = 0; i < 4; ++i) {
        int row = w * 4 + i;
        float4 zv4 = *(const float4*)&zbuf[row][c0];
        float zv[4] = {zv4.x, zv4.y, zv4.z, zv4.w};
        float pv[4];
        #pragma unroll
        for (int j = 0; j < 4; ++j) {
            int c = c0 + j;
            pv[j] = (c < N_INNER) ? 1.f / (1.f + expf(-bet[j] * (zv[j] + bia[j]))) : 0.f;
        }
        *(float4*)&zbuf[row][c0] = make_float4(pv[0], pv[1], pv[2], pv[3]);
    }
    float4 lqv[4];
    #pragma unroll
    for (int i = 0; i < 4; ++i)
        lqv[i] = *(const float4*)(logQt + (size_t)tg[i] * N_LEAF + c0);
    asm volatile("s_waitcnt lgkmcnt(0)" ::: "memory");  // wave-private writes -> own-wave reads

    float pnum[4] = {0.f, 0.f, 0.f, 0.f};
    float pden[4] = {0.f, 0.f, 0.f, 0.f};
    float loss = 0.f;

    #pragma unroll
    for (int i = 0; i < 4; ++i) {
        const float* pb = zbuf[w * 4 + i];
        const int r = m0 + w * 4 + i;
        float lqa[4] = {lqv[i].x, lqv[i].y, lqv[i].z, lqv[i].w};

        // leaf path products, factored (bit-identical association order):
        // leaves c0..c0+3 share levels d=0..5; d=6 node common (bit = j>>1);
        // d=7 node = 127 + 2*lane + (j>>1), bit = j&1.
        float P = 1.f;
        #pragma unroll
        for (int d = 0; d < 6; ++d) {
            int node = (1 << d) - 1 + (c0 >> (8 - d));
            int bit = (c0 >> (7 - d)) & 1;
            float pvn = pb[node];
            P *= bit ? pvn : (1.f - pvn);
        }
        float p6  = pb[63 + lane];
        float p7a = pb[127 + 2 * lane];
        float p7b = pb[127 + 2 * lane + 1];
        float lsum = 0.f, bestV = -1.f;
        int bestI = 0;
        #pragma unroll
        for (int j = 0; j < 4; ++j) {
            float t6 = (j & 2) ? p6 : (1.f - p6);
            float p7 = (j & 2) ? p7b : p7a;
            float t7 = (j & 1) ? p7 : (1.f - p7);
            float pl = (P * t6) * t7;
            lsum += pl * lqa[j];
            if (pl > bestV) { bestV = pl; bestI = c0 + j; }  // ascending j keeps lowest tie
        }
        if (lane < 32) {
            #pragma unroll
            for (int j = 0; j < 4; ++j) {
                int c = c0 + j;
                if (c < 127) {
                    int h = c + 1; int d = 31 - __clz(h);
                    float pp = 1.f;
                    for (int e = 0; e < d; ++e) {
                        int ha = h >> (d - e);
                        int bit = (h >> (d - 1 - e)) & 1;
                        float pvn = pb[ha - 1];
                        pp *= bit ? pvn : (1.f - pvn);
                    }
                    pnum[j] += pb[c] * pp;
                    pden[j] += pp;
                }
            }
        }
        #pragma unroll
        for (int m = 1; m < 64; m <<= 1) {
            lsum += __shfl_xor(lsum, m, 64);
            float ov = __shfl_xor(bestV, m, 64);
            int   oi = __shfl_xor(bestI, m, 64);
            if (ov > bestV || (ov == bestV && oi < bestI)) { bestV = ov; bestI = oi; }
        }
        loss += lsum;
        out[1 + (size_t)r * C_SIZE + lane]      = Q[bestI * C_SIZE + lane];
        out[1 + (size_t)r * C_SIZE + lane + 64] = Q[bestI * C_SIZE + lane + 64];
    }

    // block-level reduction via LDS atomics, then one global store per thread
    if (lane < 32) {
        #pragma unroll
        for (int j = 0; j < 4; ++j) {
            int c = c0 + j;
            if (c < 127) {
                atomicAdd(&s_num[c], pnum[j]);
                atomicAdd(&s_den[c], pden[j]);
            }
        }
    }
    if (lane == 0) atomicAdd(&s_loss, loss);
    __syncthreads();
    float* rec = partial + (size_t)blockIdx.x * 256;
    if (t < 127)        rec[t] = s_num[t];
    else if (t == 127)  rec[127] = s_loss;
    else if (t < 255)   rec[t] = s_den[t - 128];
    else                rec[255] = 0.f;
}

// ---------------- K3: reduce partials + finalize total (1024 threads: 4x parallel) ----------------
__global__ __launch_bounds__(1024) void reduce_kernel(
    const float* __restrict__ partial, float* __restrict__ out)
{
    __shared__ float part[4][256];
    __shared__ float s[256];
    __shared__ float red[128];
    const int t = threadIdx.x;
    const int col = t & 255, seg = t >> 8;           // 4 segments of 128 records
    const int base = seg * (NBLK_PATH / 4);
    float a0 = 0.f, a1 = 0.f, a2 = 0.f, a3 = 0.f;
    for (int r = 0; r < NBLK_PATH / 4; r += 4) {
        a0 += partial[(size_t)(base + r + 0) * 256 + col];
        a1 += partial[(size_t)(base + r + 1) * 256 + col];
        a2 += partial[(size_t)(base + r + 2) * 256 + col];
        a3 += partial[(size_t)(base + r + 3) * 256 + col];
    }
    part[seg][col] = (a0 + a1) + (a2 + a3);
    __syncthreads();
    if (t < 256) s[t] = (part[0][t] + part[1][t]) + (part[2][t] + part[3][t]);
    __syncthreads();
    float term = 0.f;
    if (t < 127) {
        int d = 31 - __clz(t + 1);
        float lam = 0.1f * exp2f(-(float)(d + 1));
        float pen = s[t] / s[128 + t];
        term = lam * 0.5f * (logf(pen) + logf(1.f - pen));
    }
    if (t < 128) { red[t] = term; }
    __syncthreads();
    for (int sh = 64; sh > 0; sh >>= 1) { if (t < sh) red[t] += red[t + sh]; __syncthreads(); }
    if (t == 0) out[0] = -(s[127] / (float)B_SIZE) - red[0];
}

extern "C" void kernel_launch(void* const* d_in, const int* in_sizes, int n_in,
                              void* d_out, int out_size, void* d_ws, size_t ws_size,
                              hipStream_t stream)
{
    const float* x    = (const float*)d_in[0];
    const int*   tgt  = (const int*)d_in[1];
    const float* W    = (const float*)d_in[2];
    const float* b    = (const float*)d_in[3];
    const float* beta = (const float*)d_in[4];
    const float* lp   = (const float*)d_in[5];
    float* out = (float*)d_out;

    // ws layout: Wh/Wl (u16 256x2048 each), Q (256x128 f32), logQt (128x256 f32),
    // block partials (512 x 256 f32). No z buffer any more.
    u16*   Wh      = (u16*)d_ws;
    u16*   Wl      = Wh + (size_t)N_LEAF * D_SIZE;
    float* Q       = (float*)(Wl + (size_t)N_LEAF * D_SIZE);
    float* logQt   = Q + (size_t)N_LEAF * C_SIZE;
    float* partial = logQt + (size_t)C_SIZE * N_LEAF;

    prep_kernel<<<512, 256, 0, stream>>>(W, Wh, Wl, lp, Q, logQt);

    gemm_path<<<512, 256, 0, stream>>>(x, Wh, Wl, tgt, b, beta, Q, logQt, partial, out);

    reduce_kernel<<<1, 1024, 0, stream>>>(partial, out);
}

// Round 12
// 165.884 us; speedup vs baseline: 1.4746x; 1.4746x over previous
//
#include <hip/hip_runtime.h>
#include <hip/hip_bf16.h>
#include <hip/hip_fp16.h>
#include <stdint.h>

#define B_SIZE 8192
#define D_SIZE 2048
#define C_SIZE 128
#define N_INNER 255
#define N_LEAF 256
#define NPAD 256
#define NBLK_PATH 512

typedef _Float16 half8 __attribute__((ext_vector_type(8)));
typedef __fp16 pk16x2 __attribute__((ext_vector_type(2)));   // return type of cvt_pkrtz
typedef float f32x4 __attribute__((ext_vector_type(4)));
typedef unsigned short u16;

// ---- fp32 -> (hi,lo) fp16 split, packed pairs ----
__device__ inline uint32_t pkh(float a, float b) {
    pk16x2 h = __builtin_amdgcn_cvt_pkrtz(a, b);
    return __builtin_bit_cast(uint32_t, h);
}
__device__ inline void split4(const float4 v, uint2& hi, uint2& lo) {
    pk16x2 a01 = __builtin_amdgcn_cvt_pkrtz(v.x, v.y);
    pk16x2 a23 = __builtin_amdgcn_cvt_pkrtz(v.z, v.w);
    float r0 = v.x - (float)a01[0];
    float r1 = v.y - (float)a01[1];
    float r2 = v.z - (float)a23[0];
    float r3 = v.w - (float)a23[1];
    hi = make_uint2(__builtin_bit_cast(uint32_t, a01), __builtin_bit_cast(uint32_t, a23));
    lo = make_uint2(pkh(r0, r1), pkh(r2, r3));
}
// 8 consecutive fp32 -> hi/lo half8 fragments (same arithmetic as split4 -> bit-identical)
__device__ inline void splitB8(const float4 v0, const float4 v1, half8& h, half8& l) {
    uint2 h0, l0, h1, l1;
    split4(v0, h0, l0);
    split4(v1, h1, l1);
    uint4 hh = make_uint4(h0.x, h0.y, h1.x, h1.y);
    uint4 ll = make_uint4(l0.x, l0.y, l1.x, l1.y);
    h = __builtin_bit_cast(half8, hh);
    l = __builtin_bit_cast(half8, ll);
}

// ---------------- K1 (merged): gemm tiles (bid<512) + leaf softmax (bid>=512) ----------------
// R10 structure (best measured: 166.7 total, gemm 55.8). Round-12 edits, gemm only:
//   (1) A prefetch 2-DEEP (av_c/av_n/av_n2): x A-tile loads are HBM (~900 cy latency);
//       one kt is only ~500 cy, so 1-deep prefetch stalled ~400 cy/kt at the split.
//       2-deep gives ~1000 cy of cover.
//   (2) the per-kt hard `s_waitcnt lgkmcnt(0)` replaced by a compiler-only reorder
//       barrier: LDS ops of a wave execute in program order (wave-private buffers),
//       and the ds_read register dependency gets compiler-inserted lgkmcnt(N).
// Everything else byte-identical. NOTE: launch_bounds min-waves MUST stay 2 —
// (256,4) squeezes arch-VGPR to 64 and spills ~1.1 GB scratch (R5: 380 us).
#define GBM 64
#define GBK 32
#define GKSPLIT 4
#define KCHUNK (D_SIZE / GKSPLIT)   // 512
#define KITERS (KCHUNK / GBK)       // 16
#define LDKA 40                     // padded A row stride in u16 (80 B -> 2-way bank alias = free)

__global__ __launch_bounds__(256, 2) void gemm_prep(
    const float* __restrict__ x, const float* __restrict__ W, float* __restrict__ zp,
    const float* __restrict__ lp, float* __restrict__ Q, float* __restrict__ logQt)
{
    __shared__ __align__(16) u16 sAh[4][GBM * LDKA];
    __shared__ __align__(16) u16 sAl[4][GBM * LDKA];
    __shared__ float red[128];

    const int t = threadIdx.x;

    if (blockIdx.x >= 512) {
        // ---- softmax over leaf row (block-uniform branch) ----
        int row = blockIdx.x - 512;
        float v = 0.f;
        if (t < 128) { v = lp[row * C_SIZE + t]; red[t] = v; }
        __syncthreads();
        for (int s = 64; s > 0; s >>= 1) { if (t < s) red[t] = fmaxf(red[t], red[t + s]); __syncthreads(); }
        float mx = red[0]; __syncthreads();
        float e = 0.f;
        if (t < 128) { e = expf(v - mx); red[t] = e; }
        __syncthreads();
        for (int s = 64; s > 0; s >>= 1) { if (t < s) red[t] += red[t + s]; __syncthreads(); }
        float sum = red[0];
        if (t < 128) {
            Q[row * C_SIZE + t] = e / sum;
            logQt[(size_t)t * N_LEAF + row] = (v - mx) - logf(sum);   // [class][leaf]
        }
        return;
    }

    const int lane = t & 63, w = t >> 6;
    const int lr = lane & 15, lq = lane >> 4;
    const int mi = blockIdx.x >> 2;          // m-tile index 0..127
    const int kz = blockIdx.x & 3;           // kz clustered per XCD under round-robin
    const int m0 = mi * GBM;
    const int kb0 = kz * KCHUNK;

    f32x4 acc[4][4];
    #pragma unroll
    for (int mt = 0; mt < 4; ++mt)
        #pragma unroll
        for (int nt = 0; nt < 4; ++nt) acc[mt][nt] = (f32x4){0.f, 0.f, 0.f, 0.f};

    // per-lane B row indices (row 255 doesn't exist in W: clamp that single lane to 254;
    // the resulting z column 255 is provably never consumed by path_kernel)
    int brow[4];
    #pragma unroll
    for (int nt = 0; nt < 4; ++nt) {
        int rrow = w * 64 + nt * 16 + lr;
        brow[nt] = (rrow > 254) ? 254 : rrow;
    }

    // prologue: A tiles for kt=0 and kt=1 (64 rows x 32 k fp32, 8 float4/lane, coalesced)
    float4 av_c[8], av_n[8];
    #pragma unroll
    for (int i = 0; i < 8; ++i) {
        int idx = i * 64 + lane;
        int row = idx >> 3, ch = idx & 7;
        av_c[i] = *(const float4*)(x + (size_t)(m0 + row) * D_SIZE + kb0 + ch * 4);
    }
    #pragma unroll
    for (int i = 0; i < 8; ++i) {
        int idx = i * 64 + lane;
        int row = idx >> 3, ch = idx & 7;
        av_n[i] = *(const float4*)(x + (size_t)(m0 + row) * D_SIZE + kb0 + GBK + ch * 4);
    }
    // prologue: load kt=0 B fragments (f32) and split in-register
    half8 bh[4], bl[4];
    #pragma unroll
    for (int nt = 0; nt < 4; ++nt) {
        const float* p = W + (size_t)brow[nt] * D_SIZE + kb0 + lq * 8;
        float4 b0 = *(const float4*)(p);
        float4 b1 = *(const float4*)(p + 4);
        splitB8(b0, b1, bh[nt], bl[nt]);
    }

    #pragma unroll
    for (int kt = 0; kt < KITERS; ++kt) {
        const int kb = kb0 + kt * GBK;
        // 1. issue NEXT kt's B loads (f32, consumed at rotate)
        float4 nb0[4], nb1[4];
        if (kt + 1 < KITERS) {
            #pragma unroll
            for (int nt = 0; nt < 4; ++nt) {
                const float* p = W + (size_t)brow[nt] * D_SIZE + kb + GBK + lq * 8;
                nb0[nt] = *(const float4*)(p);
                nb1[nt] = *(const float4*)(p + 4);
            }
        }
        // 2. issue A loads for kt+2 (2-deep: covers ~900 cy HBM latency)
        float4 av_n2[8];
        if (kt + 2 < KITERS) {
            #pragma unroll
            for (int i = 0; i < 8; ++i) {
                int idx = i * 64 + lane;
                int row = idx >> 3, ch = idx & 7;
                av_n2[i] = *(const float4*)(x + (size_t)(m0 + row) * D_SIZE + kb + 2 * GBK + ch * 4);
            }
        }
        // 3. split current A into this wave's private LDS region
        #pragma unroll
        for (int i = 0; i < 8; ++i) {
            int idx = i * 64 + lane;
            int row = idx >> 3, ch = idx & 7;
            uint2 hi, lo; split4(av_c[i], hi, lo);
            *(uint2*)&sAh[w][row * LDKA + ch * 4] = hi;
            *(uint2*)&sAl[w][row * LDKA + ch * 4] = lo;
        }
        // compiler reorder fence only: DS ops of a wave execute in program order, so the
        // reads below see the writes above without draining lgkmcnt to 0.
        asm volatile("" ::: "memory");
        // 4. A fragments
        half8 ah[4], al[4];
        #pragma unroll
        for (int mt = 0; mt < 4; ++mt) {
            int off = (mt * 16 + lr) * LDKA + lq * 8;
            ah[mt] = *(const half8*)&sAh[w][off];
            al[mt] = *(const half8*)&sAl[w][off];
        }
        // 5. MFMA (hi*hi + hi*lo + lo*hi)
        #pragma unroll
        for (int mt = 0; mt < 4; ++mt)
            #pragma unroll
            for (int nt = 0; nt < 4; ++nt) {
                acc[mt][nt] = __builtin_amdgcn_mfma_f32_16x16x32_f16(ah[mt], bh[nt], acc[mt][nt], 0, 0, 0);
                acc[mt][nt] = __builtin_amdgcn_mfma_f32_16x16x32_f16(ah[mt], bl[nt], acc[mt][nt], 0, 0, 0);
                acc[mt][nt] = __builtin_amdgcn_mfma_f32_16x16x32_f16(al[mt], bh[nt], acc[mt][nt], 0, 0, 0);
            }
        // 6. rotate prefetched A (2-deep) and split prefetched B f32 -> hi/lo fragments
        if (kt + 1 < KITERS) {
            #pragma unroll
            for (int i = 0; i < 8; ++i) av_c[i] = av_n[i];
            if (kt + 2 < KITERS) {
                #pragma unroll
                for (int i = 0; i < 8; ++i) av_n[i] = av_n2[i];
            }
            #pragma unroll
            for (int nt = 0; nt < 4; ++nt) splitB8(nb0[nt], nb1[nt], bh[nt], bl[nt]);
        }
    }

    float* zout = zp + (size_t)kz * B_SIZE * NPAD;
    #pragma unroll
    for (int mt = 0; mt < 4; ++mt) {
        #pragma unroll
        for (int nt = 0; nt < 4; ++nt) {
            int gn = w * 64 + nt * 16 + lr;
            #pragma unroll
            for (int r = 0; r < 4; ++r) {
                int gm = m0 + mt * 16 + lq * 4 + r;
                zout[(size_t)gm * NPAD + gn] = acc[mt][nt][r];
            }
        }
    }
}

// ---------------- K2: fused reduce + sigmoid + paths + penalties + loss + argmax gather ----------------
// R10 version (best measured): 512 blocks x 4 waves x 4 rows, rows pipelined via
// per-row pbuf slices, one fence, factored tree walks, partial-record write.
__global__ __launch_bounds__(256) void path_kernel(
    const float* __restrict__ z, const int* __restrict__ target,
    const float* __restrict__ bvec, const float* __restrict__ beta,
    const float* __restrict__ Q, const float* __restrict__ logQt,
    float* __restrict__ partial, float* __restrict__ out)
{
    __shared__ float pbuf[16][256];     // [w*4 + i]
    __shared__ float s_num[128], s_den[128], s_loss;
    const int t = threadIdx.x, w = t >> 6, lane = t & 63;
    const int c0 = lane * 4;
    float pnum[4] = {0.f, 0.f, 0.f, 0.f};
    float pden[4] = {0.f, 0.f, 0.f, 0.f};
    float loss = 0.f;

    if (t < 128) s_num[t] = 0.f;
    else s_den[t - 128] = 0.f;
    if (t == 0) s_loss = 0.f;
    __syncthreads();   // init visible to all waves before end-of-kernel atomics

    float bet[4], bia[4];
    #pragma unroll
    for (int j = 0; j < 4; ++j) {
        int c = c0 + j;
        bet[j] = (c < N_INNER) ? beta[c] : 0.f;
        bia[j] = (c < N_INNER) ? bvec[c] : 0.f;
    }

    const int rbase = blockIdx.x * 16 + w * 4;

    // ---- phase 1: all 4 rows' z partials (16 independent float4 loads), reduce ----
    float4 zs[4];
    #pragma unroll
    for (int i = 0; i < 4; ++i) {
        float4 s = make_float4(0.f, 0.f, 0.f, 0.f);
        #pragma unroll
        for (int p = 0; p < GKSPLIT; ++p) {
            float4 v = *(const float4*)(z + ((size_t)p * B_SIZE + rbase + i) * NPAD + c0);
            s.x += v.x; s.y += v.y; s.z += v.z; s.w += v.w;
        }
        zs[i] = s;
    }
    int tg[4];
    #pragma unroll
    for (int i = 0; i < 4; ++i) tg[i] = target[rbase + i];

    // sigmoid all 4 rows, store each to its own pbuf slice
    #pragma unroll
    for (int i = 0; i < 4; ++i) {
        float zv[4] = {zs[i].x, zs[i].y, zs[i].z, zs[i].w};
        float pv[4];
        #pragma unroll
        for (int j = 0; j < 4; ++j) {
            int c = c0 + j;
            pv[j] = (c < N_INNER) ? 1.f / (1.f + expf(-bet[j] * (zv[j] + bia[j]))) : 0.f;
        }
        *(float4*)&pbuf[w * 4 + i][c0] = make_float4(pv[0], pv[1], pv[2], pv[3]);
    }
    float4 lq[4];
    #pragma unroll
    for (int i = 0; i < 4; ++i)
        lq[i] = *(const float4*)(logQt + (size_t)tg[i] * N_LEAF + c0);
    asm volatile("s_waitcnt lgkmcnt(0)" ::: "memory");  // wave-private LDS: one fence for all slices

    // ---- phase 2: 4 back-to-back tree walks (all data now in LDS/regs) ----
    #pragma unroll
    for (int i = 0; i < 4; ++i) {
        const float* pb = pbuf[w * 4 + i];
        const int r = rbase + i;
        float lqa[4] = {lq[i].x, lq[i].y, lq[i].z, lq[i].w};

        // leaf path products, factored (bit-identical association order):
        // leaves c0..c0+3 share levels d=0..5; d=6 node common (bit = j>>1);
        // d=7 node = 127 + 2*lane + (j>>1), bit = j&1.
        float P = 1.f;
        #pragma unroll
        for (int d = 0; d < 6; ++d) {
            int node = (1 << d) - 1 + (c0 >> (8 - d));
            int bit = (c0 >> (7 - d)) & 1;
            float pvn = pb[node];
            P *= bit ? pvn : (1.f - pvn);
        }
        float p6  = pb[63 + lane];
        float p7a = pb[127 + 2 * lane];
        float p7b = pb[127 + 2 * lane + 1];
        float lsum = 0.f, bestV = -1.f;
        int bestI = 0;
        #pragma unroll
        for (int j = 0; j < 4; ++j) {
            float t6 = (j & 2) ? p6 : (1.f - p6);
            float p7 = (j & 2) ? p7b : p7a;
            float t7 = (j & 1) ? p7 : (1.f - p7);
            float pl = (P * t6) * t7;
            lsum += pl * lqa[j];
            if (pl > bestV) { bestV = pl; bestI = c0 + j; }  // ascending j keeps lowest tie
        }
        if (lane < 32) {
            #pragma unroll
            for (int j = 0; j < 4; ++j) {
                int c = c0 + j;
                if (c < 127) {
                    int h = c + 1; int d = 31 - __clz(h);
                    float pp = 1.f;
                    for (int e = 0; e < d; ++e) {
                        int ha = h >> (d - e);
                        int bit = (h >> (d - 1 - e)) & 1;
                        float pvn = pb[ha - 1];
                        pp *= bit ? pvn : (1.f - pvn);
                    }
                    pnum[j] += pb[c] * pp;
                    pden[j] += pp;
                }
            }
        }
        #pragma unroll
        for (int m = 1; m < 64; m <<= 1) {
            lsum += __shfl_xor(lsum, m, 64);
            float ov = __shfl_xor(bestV, m, 64);
            int   oi = __shfl_xor(bestI, m, 64);
            if (ov > bestV || (ov == bestV && oi < bestI)) { bestV = ov; bestI = oi; }
        }
        loss += lsum;
        out[1 + (size_t)r * C_SIZE + lane]      = Q[bestI * C_SIZE + lane];
        out[1 + (size_t)r * C_SIZE + lane + 64] = Q[bestI * C_SIZE + lane + 64];
    }

    // block-level reduction via LDS atomics, then one global store per thread
    if (lane < 32) {
        #pragma unroll
        for (int j = 0; j < 4; ++j) {
            int c = c0 + j;
            if (c < 127) {
                atomicAdd(&s_num[c], pnum[j]);
                atomicAdd(&s_den[c], pden[j]);
            }
        }
    }
    if (lane == 0) atomicAdd(&s_loss, loss);
    __syncthreads();
    float* rec = partial + (size_t)blockIdx.x * 256;
    if (t < 127)        rec[t] = s_num[t];
    else if (t == 127)  rec[127] = s_loss;
    else if (t < 255)   rec[t] = s_den[t - 128];
    else                rec[255] = 0.f;
}

// ---------------- K3: reduce partials + finalize total (1024 threads: 4x parallel) ----------------
__global__ __launch_bounds__(1024) void reduce_kernel(
    const float* __restrict__ partial, float* __restrict__ out)
{
    __shared__ float part[4][256];
    __shared__ float s[256];
    __shared__ float red[128];
    const int t = threadIdx.x;
    const int col = t & 255, seg = t >> 8;           // 4 segments of 128 records
    const int base = seg * (NBLK_PATH / 4);
    float a0 = 0.f, a1 = 0.f, a2 = 0.f, a3 = 0.f;
    for (int r = 0; r < NBLK_PATH / 4; r += 4) {
        a0 += partial[(size_t)(base + r + 0) * 256 + col];
        a1 += partial[(size_t)(base + r + 1) * 256 + col];
        a2 += partial[(size_t)(base + r + 2) * 256 + col];
        a3 += partial[(size_t)(base + r + 3) * 256 + col];
    }
    part[seg][col] = (a0 + a1) + (a2 + a3);
    __syncthreads();
    if (t < 256) s[t] = (part[0][t] + part[1][t]) + (part[2][t] + part[3][t]);
    __syncthreads();
    float term = 0.f;
    if (t < 127) {
        int d = 31 - __clz(t + 1);
        float lam = 0.1f * exp2f(-(float)(d + 1));
        float pen = s[t] / s[128 + t];
        term = lam * 0.5f * (logf(pen) + logf(1.f - pen));
    }
    if (t < 128) { red[t] = term; }
    __syncthreads();
    for (int sh = 64; sh > 0; sh >>= 1) { if (t < sh) red[t] += red[t + sh]; __syncthreads(); }
    if (t == 0) out[0] = -(s[127] / (float)B_SIZE) - red[0];
}

extern "C" void kernel_launch(void* const* d_in, const int* in_sizes, int n_in,
                              void* d_out, int out_size, void* d_ws, size_t ws_size,
                              hipStream_t stream)
{
    const float* x    = (const float*)d_in[0];
    const int*   tgt  = (const int*)d_in[1];
    const float* W    = (const float*)d_in[2];
    const float* b    = (const float*)d_in[3];
    const float* beta = (const float*)d_in[4];
    const float* lp   = (const float*)d_in[5];
    float* out = (float*)d_out;

    // ws layout (floats): z partials (4 x 8192 x 256), Q (256x128), logQt (128x256),
    // block partials (512 x 256)
    float* z       = (float*)d_ws;
    float* Q       = z + (size_t)GKSPLIT * B_SIZE * NPAD;
    float* logQt   = Q + (size_t)N_LEAF * C_SIZE;
    float* partial = logQt + (size_t)C_SIZE * N_LEAF;

    // merged launch: blocks 0..511 gemm tiles (kz = bid & 3 XCD clustering),
    // blocks 512..767 leaf softmax
    gemm_prep<<<768, 256, 0, stream>>>(x, W, z, lp, Q, logQt);

    path_kernel<<<NBLK_PATH, 256, 0, stream>>>(
        z, tgt, b, beta, Q, logQt, partial, out);

    reduce_kernel<<<1, 1024, 0, stream>>>(partial, out);
}